// Round 1
// baseline (627.969 us; speedup 1.0000x reference)
//
#include <hip/hip_runtime.h>

// Problem constants (reference: N=65536, D=512, S=262144)
#define NROWS 65536
#define DCOLS 512
#define D4    128   // float4 per row

// ---------------------------------------------------------------------------
// Kernel 1: inclusive prefix sum of feeds_repeat_times (N=65536) into cum[].
// Single block: 1024 threads x 64 elements each. Per-thread sequential scan,
// Hillis-Steele over 1024 partials in LDS, then add exclusive offset.
// ---------------------------------------------------------------------------
__global__ __launch_bounds__(1024) void scan_kernel(const int* __restrict__ rep,
                                                    int* __restrict__ cum) {
    __shared__ int sdata[1024];
    const int t = threadIdx.x;
    const int base = t * 64;

    int v[64];
    const int4* rep4 = (const int4*)(rep + base);
#pragma unroll
    for (int k = 0; k < 16; ++k) {
        int4 x = rep4[k];
        v[4 * k + 0] = x.x; v[4 * k + 1] = x.y;
        v[4 * k + 2] = x.z; v[4 * k + 3] = x.w;
    }
    int partial = 0;
#pragma unroll
    for (int k = 0; k < 64; ++k) partial += v[k];

    sdata[t] = partial;
    __syncthreads();
    for (int off = 1; off < 1024; off <<= 1) {
        int add = (t >= off) ? sdata[t - off] : 0;
        __syncthreads();
        sdata[t] += add;
        __syncthreads();
    }
    int running = sdata[t] - partial;  // exclusive prefix of this thread's chunk
#pragma unroll
    for (int k = 0; k < 64; ++k) { running += v[k]; v[k] = running; }

    int4* cum4 = (int4*)(cum + base);
#pragma unroll
    for (int k = 0; k < 16; ++k) {
        int4 x;
        x.x = v[4 * k + 0]; x.y = v[4 * k + 1];
        x.z = v[4 * k + 2]; x.w = v[4 * k + 3];
        cum4[k] = x;
    }
}

// ---------------------------------------------------------------------------
// Kernel 2: zero rows [total, S). Grid-stride starting at the tail, so no
// wasted work over valid rows. Coalesced float4 stores.
// ---------------------------------------------------------------------------
__global__ __launch_bounds__(256) void zero_tail_kernel(const int* __restrict__ cum,
                                                        float4* __restrict__ out,
                                                        int S) {
    int total = cum[NROWS - 1];
    if (total > S) total = S;
    const long long startE = (long long)total * D4;
    const long long endE   = (long long)S * D4;
    const long long stride = (long long)gridDim.x * blockDim.x;
    const float4 z = make_float4(0.f, 0.f, 0.f, 0.f);
    for (long long e = startE + (long long)blockIdx.x * blockDim.x + threadIdx.x;
         e < endE; e += stride) {
        out[e] = z;
    }
}

// ---------------------------------------------------------------------------
// Kernel 3: scatter. One wave (64 lanes) per source row. Load the 2 KB row
// once (2 x float4 per lane), store it r_i times to rows [cum[i]-r_i, cum[i]),
// clipped to S. Destination ranges are disjoint across rows.
// ---------------------------------------------------------------------------
__global__ __launch_bounds__(256) void scatter_kernel(const float* __restrict__ feeds,
                                                      const int* __restrict__ rep,
                                                      const int* __restrict__ cum,
                                                      float* __restrict__ out,
                                                      int S) {
    const int wave = (int)((blockIdx.x * blockDim.x + threadIdx.x) >> 6);
    const int lane = threadIdx.x & 63;
    if (wave >= NROWS) return;

    const int r = rep[wave];
    if (r == 0) return;
    const int end   = cum[wave];
    const int start = end - r;
    if (start >= S) return;

    const float4* src = (const float4*)(feeds + (long long)wave * DCOLS);
    const float4 a = src[lane];
    const float4 b = src[lane + 64];

    const int stop = end < S ? end : S;
    for (int j = start; j < stop; ++j) {
        float4* dst = (float4*)(out + (long long)j * DCOLS);
        dst[lane]      = a;
        dst[lane + 64] = b;
    }
}

extern "C" void kernel_launch(void* const* d_in, const int* in_sizes, int n_in,
                              void* d_out, int out_size, void* d_ws, size_t ws_size,
                              hipStream_t stream) {
    const float* feeds = (const float*)d_in[0];
    const int*   rep   = (const int*)d_in[1];
    // d_in[2] is the scalar output_feeds_size; S also derivable from out_size.
    const int S = out_size / DCOLS;

    int* cum = (int*)d_ws;  // 65536 ints = 256 KB of workspace

    scan_kernel<<<1, 1024, 0, stream>>>(rep, cum);
    zero_tail_kernel<<<2048, 256, 0, stream>>>(cum, (float4*)d_out, S);
    scatter_kernel<<<NROWS / 4, 256, 0, stream>>>(feeds, rep, cum, (float*)d_out, S);
}

// Round 3
// 608.687 us; speedup vs baseline: 1.0317x; 1.0317x over previous
//
#include <hip/hip_runtime.h>

// Problem constants (reference: N=65536, D=512, S=262144)
#define NROWS 65536
#define DCOLS 512
#define D4    128   // float4 per row

// Native 16B vector type usable with __builtin_nontemporal_store
// (HIP_vector_type float4 is rejected by the builtin).
typedef float f32x4 __attribute__((ext_vector_type(4)));

// ---------------------------------------------------------------------------
// Kernel 1: inclusive prefix sum of feeds_repeat_times (N=65536) into cum[].
// Single block: 1024 threads x 64 elements each. Per-thread sequential scan,
// Hillis-Steele over 1024 partials in LDS, then add exclusive offset.
// ---------------------------------------------------------------------------
__global__ __launch_bounds__(1024) void scan_kernel(const int* __restrict__ rep,
                                                    int* __restrict__ cum) {
    __shared__ int sdata[1024];
    const int t = threadIdx.x;
    const int base = t * 64;

    int4 v[16];
    const int4* rep4 = (const int4*)(rep + base);
#pragma unroll
    for (int k = 0; k < 16; ++k) v[k] = rep4[k];

    int partial = 0;
#pragma unroll
    for (int k = 0; k < 16; ++k) partial += v[k].x + v[k].y + v[k].z + v[k].w;

    sdata[t] = partial;
    __syncthreads();
    for (int off = 1; off < 1024; off <<= 1) {
        int add = (t >= off) ? sdata[t - off] : 0;
        __syncthreads();
        sdata[t] += add;
        __syncthreads();
    }
    int running = sdata[t] - partial;  // exclusive prefix of this thread's chunk

    int4* cum4 = (int4*)(cum + base);
#pragma unroll
    for (int k = 0; k < 16; ++k) {
        int4 x;
        running += v[k].x; x.x = running;
        running += v[k].y; x.y = running;
        running += v[k].z; x.z = running;
        running += v[k].w; x.w = running;
        cum4[k] = x;
    }
}

// ---------------------------------------------------------------------------
// Kernel 2: build idx[j] = source row for every valid output row j.
// One thread per source row; writes r_i ints to [cum[i]-r_i, cum[i]).
// Total ~1 MiB of writes — cheap.
// ---------------------------------------------------------------------------
__global__ __launch_bounds__(256) void build_idx_kernel(const int* __restrict__ rep,
                                                        const int* __restrict__ cum,
                                                        int* __restrict__ idx,
                                                        int S) {
    const int i = blockIdx.x * blockDim.x + threadIdx.x;
    if (i >= NROWS) return;
    const int end   = cum[i];
    const int r     = rep[i];
    const int start = end - r;
    if (r == 0 || start >= S) return;
    const int stop = end < S ? end : S;
    for (int j = start; j < stop; ++j) idx[j] = i;
}

// ---------------------------------------------------------------------------
// Kernel 3: gather. One wave (64 lanes) per OUTPUT row. Uniform work:
// read idx[j] (broadcast), copy 2 KB source row -> 2 KB dest row, or write
// zeros for the padding tail. Nontemporal stores keep the streaming output
// from evicting feeds (128 MiB, L3-resident) out of the 256 MiB L3.
// ---------------------------------------------------------------------------
__global__ __launch_bounds__(256) void gather_kernel(const f32x4* __restrict__ feeds,
                                                     const int* __restrict__ idx,
                                                     const int* __restrict__ cum,
                                                     f32x4* __restrict__ out,
                                                     int S) {
    const int wave = (int)((blockIdx.x * blockDim.x + threadIdx.x) >> 6);
    const int lane = threadIdx.x & 63;
    if (wave >= S) return;

    const int total = cum[NROWS - 1];

    f32x4 a = (f32x4)0.f;
    f32x4 b = (f32x4)0.f;
    if (wave < total) {
        const int si = idx[wave];
        const f32x4* src = feeds + (long long)si * D4;
        a = src[lane];
        b = src[lane + 64];
    }
    f32x4* dst = out + (long long)wave * D4;
    __builtin_nontemporal_store(a, dst + lane);
    __builtin_nontemporal_store(b, dst + lane + 64);
}

extern "C" void kernel_launch(void* const* d_in, const int* in_sizes, int n_in,
                              void* d_out, int out_size, void* d_ws, size_t ws_size,
                              hipStream_t stream) {
    const float* feeds = (const float*)d_in[0];
    const int*   rep   = (const int*)d_in[1];
    const int S = out_size / DCOLS;

    int* cum = (int*)d_ws;            // 65536 ints = 256 KB
    int* idx = (int*)d_ws + NROWS;    // S ints = 1 MiB

    scan_kernel<<<1, 1024, 0, stream>>>(rep, cum);
    build_idx_kernel<<<NROWS / 256, 256, 0, stream>>>(rep, cum, idx, S);
    // One wave per output row: S waves -> S*64 threads / 256 = S/4 blocks.
    gather_kernel<<<S / 4, 256, 0, stream>>>((const f32x4*)feeds, idx, cum,
                                             (f32x4*)d_out, S);
}